// Round 4
// baseline (430.506 us; speedup 1.0000x reference)
//
#include <hip/hip_runtime.h>
#include <hip/hip_bf16.h>
#include <stdint.h>

#define T_DIM 16
#define B_DIM 4096
#define D_DIM 256
#define H_DIM 512
#define E_DIM 32
#define M_DIM (T_DIM * B_DIM)      // 65536 rows for the GEMMs
#define BD_DIM (B_DIM * D_DIM)     // 1048576 elems per t-slice
#define EPS_F 0.1f

typedef __attribute__((ext_vector_type(8))) short short8;   // 8 bf16 = 4 VGPRs (MFMA A/B frag)
typedef __attribute__((ext_vector_type(4))) float f32x4;    // MFMA C/D frag; also clang vec for nontemporal

#define GLOBAL_AS __attribute__((address_space(1)))
#define LDS_AS __attribute__((address_space(3)))

__device__ __forceinline__ uint32_t f2bf_rne(float x) {
  uint32_t u = __float_as_uint(x);
  return (u + 0x7fffu + ((u >> 16) & 1u)) >> 16;
}

__device__ __forceinline__ uint4 pack8(const float* f) {
  uint4 v;
  v.x = f2bf_rne(f[0]) | (f2bf_rne(f[1]) << 16);
  v.y = f2bf_rne(f[2]) | (f2bf_rne(f[3]) << 16);
  v.z = f2bf_rne(f[4]) | (f2bf_rne(f[5]) << 16);
  v.w = f2bf_rne(f[6]) | (f2bf_rne(f[7]) << 16);
  return v;
}

// ---- prep: convert f32 W1 (DxH) -> bf16 W1T (HxD); f32 W2 (HxD) -> bf16 W2T (DxH) ----
__global__ __launch_bounds__(256) void prep_kernel(
    const float* __restrict__ W1, const float* __restrict__ W2,
    uint16_t* __restrict__ W1T, uint16_t* __restrict__ W2T) {
  int idx = blockIdx.x * 256 + threadIdx.x;   // 0 .. 131071 (== D*H == H*D)
  if (idx < D_DIM * H_DIM) {
    int d = idx / H_DIM, h = idx % H_DIM;
    W1T[h * D_DIM + d] = (uint16_t)f2bf_rne(W1[idx]);   // W1T[h][d] = W1[d][h]
    int h2 = idx / D_DIM, d2 = idx % D_DIM;
    W2T[d2 * H_DIM + h2] = (uint16_t)f2bf_rne(W2[idx]); // W2T[d][h] = W2[h][d]
  }
}

// ---- agg = EPS*term + gathered edge messages (round-2 version: t-parallel, branchy) ----
// Three agg structures all plateau at ~2.6 TB/s; this one measured fastest (98 us, VGPR 20).
__global__ __launch_bounds__(256) void agg_kernel(
    const float* __restrict__ term, const float* __restrict__ pred,
    const float* __restrict__ inv, const float* __restrict__ signs,
    const int* __restrict__ heads, const int* __restrict__ tails,
    uint16_t* __restrict__ agg) {
  __shared__ int sh_h[E_DIM], sh_t[E_DIM];
  __shared__ float sh_s[E_DIM];
  if (threadIdx.x < E_DIM) {
    int e = threadIdx.x;
    sh_h[e] = heads[e] & (T_DIM - 1);   // defensive clamp, values are 0..15
    sh_t[e] = tails[e] & (T_DIM - 1);
    sh_s[e] = signs[e];
  }
  __syncthreads();

  const int t = blockIdx.y;                            // one t-slice per block row
  const int j = (blockIdx.x * 256 + threadIdx.x) * 8;  // elem offset in [0, B*D)

  float acc[8];
  {
    f32x4 a = *reinterpret_cast<const f32x4*>(term + (size_t)t * BD_DIM + j);
    f32x4 b = *reinterpret_cast<const f32x4*>(term + (size_t)t * BD_DIM + j + 4);
    acc[0] = EPS_F * a[0]; acc[1] = EPS_F * a[1]; acc[2] = EPS_F * a[2]; acc[3] = EPS_F * a[3];
    acc[4] = EPS_F * b[0]; acc[5] = EPS_F * b[1]; acc[6] = EPS_F * b[2]; acc[7] = EPS_F * b[3];
  }

#pragma unroll 1
  for (int e = 0; e < E_DIM; ++e) {
    const float s = sh_s[e];
    if (sh_t[e] == t) {   // wave-uniform branch
      const f32x4* p = reinterpret_cast<const f32x4*>(pred + (size_t)e * BD_DIM + j);
      const float* hrow = term + (size_t)sh_h[e] * BD_DIM + j;
      f32x4 p0 = __builtin_nontemporal_load(p);
      f32x4 p1 = __builtin_nontemporal_load(p + 1);
      f32x4 h0 = *reinterpret_cast<const f32x4*>(hrow);
      f32x4 h1 = *reinterpret_cast<const f32x4*>(hrow + 4);
      acc[0] += s * (h0[0] + p0[0]); acc[1] += s * (h0[1] + p0[1]);
      acc[2] += s * (h0[2] + p0[2]); acc[3] += s * (h0[3] + p0[3]);
      acc[4] += s * (h1[0] + p1[0]); acc[5] += s * (h1[1] + p1[1]);
      acc[6] += s * (h1[2] + p1[2]); acc[7] += s * (h1[3] + p1[3]);
    }
    if (sh_h[e] == t) {   // wave-uniform branch
      const f32x4* iv = reinterpret_cast<const f32x4*>(inv + (size_t)e * BD_DIM + j);
      const float* trow = term + (size_t)sh_t[e] * BD_DIM + j;
      f32x4 i0 = __builtin_nontemporal_load(iv);
      f32x4 i1 = __builtin_nontemporal_load(iv + 1);
      f32x4 t0 = *reinterpret_cast<const f32x4*>(trow);
      f32x4 t1 = *reinterpret_cast<const f32x4*>(trow + 4);
      acc[0] += s * (t0[0] + i0[0]); acc[1] += s * (t0[1] + i0[1]);
      acc[2] += s * (t0[2] + i0[2]); acc[3] += s * (t0[3] + i0[3]);
      acc[4] += s * (t1[0] + i1[0]); acc[5] += s * (t1[1] + i1[1]);
      acc[6] += s * (t1[2] + i1[2]); acc[7] += s * (t1[3] + i1[3]);
    }
  }
  *reinterpret_cast<uint4*>(agg + (size_t)t * BD_DIM + j) = pack8(acc);
}

// ---- W-resident bf16 GEMM: C[M,N] = act(A[M,K] * Bt[N,K]^T + bias) ----
// Key change vs m97 structure: the weight slice (BN x K = 64 KB) is staged into LDS ONCE
// per block (W1T/W2T are tiny, K is small), so the K-loop stages ONLY the A-chunk
// (128 x 64 = 16 KB) per step, with half the barrier count (BK=64).
// LDS = 64 + 16 = 80 KB -> 2 blocks/CU. Subtile layout [kc][n][32] keeps the proven
// m97 64-byte row stride (same bank profile as baseline).
// block = 256 thr / 4 waves; block tile 128 x BN; wave tile WM x WN.
template <int M, int N, int K, int BN, int WM, int WN, bool RELU, bool OUT_F32>
__global__ __launch_bounds__(256) void gemm_wres(
    const uint16_t* __restrict__ A, const uint16_t* __restrict__ Bt,
    const float* __restrict__ bias, void* __restrict__ Cout) {
  static_assert(BN * K == 32768, "W slice must be exactly 64 KB");
  static_assert((128 / WM) * (BN / WN) == 4, "4 waves must tile the block");
  __shared__ __align__(16) uint16_t Ws[BN * K];     // [K/32][BN][32] subtiles, 64 KB
  __shared__ __align__(16) uint16_t As[128 * 64];   // [2][128][32] subtiles, 16 KB

  constexpr int MI = WM / 16;
  constexpr int NJ = WN / 16;
  constexpr int WGM = 128 / WM;

  const int tid = threadIdx.x;
  const int w = tid >> 6;         // wave 0..3
  const int l = tid & 63;
  const int lane16 = l & 15;
  const int quad = l >> 4;
  const int wm = (w % WGM) * WM;
  const int wn = (w / WGM) * WN;
  const int m0 = blockIdx.x * 128;
  const int n0 = blockIdx.y * BN;

  // ---- stage the full W slice (BN x K) once; linear LDS dest (gload_lds contract) ----
#pragma unroll
  for (int p = 0; p < 16; ++p) {
    const int off = p * 2048 + tid * 8;           // elem offset in Ws
    const int kc = off / (BN * 32);               // k-subtile
    const int rem = off - kc * (BN * 32);
    const int n = rem >> 5;
    const int c = rem & 31;
    const uint16_t* g = Bt + (size_t)(n0 + n) * K + kc * 32 + c;
    __builtin_amdgcn_global_load_lds((const GLOBAL_AS uint32_t*)g,
                                     (LDS_AS uint32_t*)(Ws + off), 16, 0, 0);
  }

  f32x4 acc[MI][NJ];
#pragma unroll
  for (int i = 0; i < MI; ++i)
#pragma unroll
    for (int j = 0; j < NJ; ++j) acc[i][j] = (f32x4){0.f, 0.f, 0.f, 0.f};

  for (int t = 0; t < K / 64; ++t) {
    // stage A chunk 128x64 as two [128][32] subtiles (linear dest within each pass)
#pragma unroll
    for (int c = 0; c < 4; ++c) {
      const int off = c * 2048 + tid * 8;         // elem offset in As
      const int s = off >> 12;                    // which 32-k subtile
      const int row = (off >> 5) & 127;
      const int cc = off & 31;
      const uint16_t* ga = A + (size_t)(m0 + row) * K + t * 64 + s * 32 + cc;
      __builtin_amdgcn_global_load_lds((const GLOBAL_AS uint32_t*)ga,
                                       (LDS_AS uint32_t*)(As + off), 16, 0, 0);
    }
    __syncthreads();   // drains vmcnt(0): A chunk (and W on first iter) resident

    short8 af[2][MI], bfr[2][NJ];
#pragma unroll
    for (int s = 0; s < 2; ++s) {
#pragma unroll
      for (int i = 0; i < MI; ++i)
        af[s][i] = *reinterpret_cast<const short8*>(
            As + s * 4096 + (wm + i * 16 + lane16) * 32 + quad * 8);
#pragma unroll
      for (int j = 0; j < NJ; ++j)
        bfr[s][j] = *reinterpret_cast<const short8*>(
            Ws + (t * 2 + s) * (BN * 32) + (wn + j * 16 + lane16) * 32 + quad * 8);
    }
#pragma unroll
    for (int s = 0; s < 2; ++s)
#pragma unroll
      for (int i = 0; i < MI; ++i)
#pragma unroll
        for (int j = 0; j < NJ; ++j)
          acc[i][j] = __builtin_amdgcn_mfma_f32_16x16x32_bf16(af[s][i], bfr[s][j], acc[i][j], 0, 0, 0);
    __syncthreads();   // protect As before next stage overwrites
  }

  // epilogue: C/D layout col=lane&15, row=quad*4+reg (m89-verified)
#pragma unroll
  for (int j = 0; j < NJ; ++j) {
    const int col = n0 + wn + j * 16 + lane16;
    const float bv = bias[col];
#pragma unroll
    for (int i = 0; i < MI; ++i) {
#pragma unroll
      for (int r = 0; r < 4; ++r) {
        const int row = m0 + wm + i * 16 + quad * 4 + r;
        float x = acc[i][j][r] + bv;
        if (RELU) x = fmaxf(x, 0.f);
        if (OUT_F32) {
          ((float*)Cout)[(size_t)row * N + col] = x;
        } else {
          ((uint16_t*)Cout)[(size_t)row * N + col] = (uint16_t)f2bf_rne(x);
        }
      }
    }
  }
}

extern "C" void kernel_launch(void* const* d_in, const int* in_sizes, int n_in,
                              void* d_out, int out_size, void* d_ws, size_t ws_size,
                              hipStream_t stream) {
  const float* term  = (const float*)d_in[0];
  const float* pred  = (const float*)d_in[1];
  const float* inv   = (const float*)d_in[2];
  const float* signs = (const float*)d_in[3];
  const float* W1    = (const float*)d_in[4];
  const float* b1    = (const float*)d_in[5];
  const float* W2    = (const float*)d_in[6];
  const float* b2    = (const float*)d_in[7];
  const int* heads   = (const int*)d_in[8];
  const int* tails   = (const int*)d_in[9];

  char* ws = (char*)d_ws;
  uint16_t* W1T    = (uint16_t*)(ws);                          // 512*256*2   = 256 KB
  uint16_t* W2T    = (uint16_t*)(ws + 262144);                 // 256*512*2   = 256 KB
  uint16_t* agg    = (uint16_t*)(ws + 524288);                 // 65536*256*2 = 32 MB
  uint16_t* hidden = (uint16_t*)(ws + 524288 + 33554432);      // 65536*512*2 = 64 MB

  prep_kernel<<<dim3(512), dim3(256), 0, stream>>>(W1, W2, W1T, W2T);
  agg_kernel<<<dim3(BD_DIM / 8 / 256, T_DIM), dim3(256), 0, stream>>>(
      term, pred, inv, signs, heads, tails, agg);
  // gemm1: hidden[65536,512] = relu(agg x W1T^T + b1); BN=128, wave 64x64
  gemm_wres<M_DIM, H_DIM, D_DIM, 128, 64, 64, true, false>
      <<<dim3(M_DIM / 128, H_DIM / 128), dim3(256), 0, stream>>>(agg, W1T, b1, (void*)hidden);
  // gemm2: out[65536,256] = hidden x W2T^T + b2; BN=64, wave 32x64
  gemm_wres<M_DIM, D_DIM, H_DIM, 64, 32, 64, false, true>
      <<<dim3(M_DIM / 128, D_DIM / 64), dim3(256), 0, stream>>>(hidden, W2T, b2, d_out);
}

// Round 6
// 429.010 us; speedup vs baseline: 1.0035x; 1.0035x over previous
//
#include <hip/hip_runtime.h>
#include <hip/hip_bf16.h>
#include <stdint.h>

#define T_DIM 16
#define B_DIM 4096
#define D_DIM 256
#define H_DIM 512
#define E_DIM 32
#define M_DIM (T_DIM * B_DIM)      // 65536 rows for the GEMMs
#define BD_DIM (B_DIM * D_DIM)     // 1048576 elems per t-slice
#define EPS_F 0.1f

#define NSLICE 16                  // H / SH
#define SH 32                      // h-columns per slice
#define HS_LD 40                   // Hs leading dim (pad 32->40: 16B-aligned b128, bank-spread)

typedef __attribute__((ext_vector_type(8))) short short8;   // 8 bf16 = 4 VGPRs (MFMA A/B frag)
typedef __attribute__((ext_vector_type(4))) float f32x4;    // MFMA C/D frag; clang vec (nontemporal ok)

#define GLOBAL_AS __attribute__((address_space(1)))
#define LDS_AS __attribute__((address_space(3)))

__device__ __forceinline__ uint32_t f2bf_rne(float x) {
  uint32_t u = __float_as_uint(x);
  return (u + 0x7fffu + ((u >> 16) & 1u)) >> 16;
}

__device__ __forceinline__ uint4 pack8(const float* f) {
  uint4 v;
  v.x = f2bf_rne(f[0]) | (f2bf_rne(f[1]) << 16);
  v.y = f2bf_rne(f[2]) | (f2bf_rne(f[3]) << 16);
  v.z = f2bf_rne(f[4]) | (f2bf_rne(f[5]) << 16);
  v.w = f2bf_rne(f[6]) | (f2bf_rne(f[7]) << 16);
  return v;
}

// ---- agg+prep combined: blockIdx.y < 16 -> agg t-slice; blockIdx.y == 16 -> weight prep ----
// agg path is the proven round-2 kernel (98 us). prep rides along in 512 spare blocks (free).
__global__ __launch_bounds__(256) void agg_prep_kernel(
    const float* __restrict__ term, const float* __restrict__ pred,
    const float* __restrict__ inv, const float* __restrict__ signs,
    const int* __restrict__ heads, const int* __restrict__ tails,
    const float* __restrict__ W1, const float* __restrict__ W2,
    uint16_t* __restrict__ agg, uint16_t* __restrict__ W1T, uint16_t* __restrict__ W2T) {
  if (blockIdx.y == T_DIM) {  // ---- prep path: transpose+cvt both weight matrices ----
    const int idx = blockIdx.x * 256 + threadIdx.x;     // 0 .. 131071 == D*H
    const int d = idx >> 9, h = idx & (H_DIM - 1);      // idx = d*H + h
    W1T[h * D_DIM + d] = (uint16_t)f2bf_rne(W1[idx]);   // W1T[h][d] = W1[d][h]
    const int h2 = idx >> 8, d2 = idx & (D_DIM - 1);    // idx = h2*D + d2
    W2T[d2 * H_DIM + h2] = (uint16_t)f2bf_rne(W2[idx]); // W2T[d][h] = W2[h][d]
    return;
  }

  __shared__ int sh_h[E_DIM], sh_t[E_DIM];
  __shared__ float sh_s[E_DIM];
  if (threadIdx.x < E_DIM) {
    int e = threadIdx.x;
    sh_h[e] = heads[e] & (T_DIM - 1);   // defensive clamp, values are 0..15
    sh_t[e] = tails[e] & (T_DIM - 1);
    sh_s[e] = signs[e];
  }
  __syncthreads();

  const int t = blockIdx.y;                            // one t-slice per block row
  const int j = (blockIdx.x * 256 + threadIdx.x) * 8;  // elem offset in [0, B*D)

  float acc[8];
  {
    f32x4 a = *reinterpret_cast<const f32x4*>(term + (size_t)t * BD_DIM + j);
    f32x4 b = *reinterpret_cast<const f32x4*>(term + (size_t)t * BD_DIM + j + 4);
    acc[0] = EPS_F * a[0]; acc[1] = EPS_F * a[1]; acc[2] = EPS_F * a[2]; acc[3] = EPS_F * a[3];
    acc[4] = EPS_F * b[0]; acc[5] = EPS_F * b[1]; acc[6] = EPS_F * b[2]; acc[7] = EPS_F * b[3];
  }

#pragma unroll 1
  for (int e = 0; e < E_DIM; ++e) {
    const float s = sh_s[e];
    if (sh_t[e] == t) {   // wave-uniform branch
      const f32x4* p = reinterpret_cast<const f32x4*>(pred + (size_t)e * BD_DIM + j);
      const float* hrow = term + (size_t)sh_h[e] * BD_DIM + j;
      f32x4 p0 = __builtin_nontemporal_load(p);
      f32x4 p1 = __builtin_nontemporal_load(p + 1);
      f32x4 h0 = *reinterpret_cast<const f32x4*>(hrow);
      f32x4 h1 = *reinterpret_cast<const f32x4*>(hrow + 4);
      acc[0] += s * (h0[0] + p0[0]); acc[1] += s * (h0[1] + p0[1]);
      acc[2] += s * (h0[2] + p0[2]); acc[3] += s * (h0[3] + p0[3]);
      acc[4] += s * (h1[0] + p1[0]); acc[5] += s * (h1[1] + p1[1]);
      acc[6] += s * (h1[2] + p1[2]); acc[7] += s * (h1[3] + p1[3]);
    }
    if (sh_h[e] == t) {   // wave-uniform branch
      const f32x4* iv = reinterpret_cast<const f32x4*>(inv + (size_t)e * BD_DIM + j);
      const float* trow = term + (size_t)sh_t[e] * BD_DIM + j;
      f32x4 i0 = __builtin_nontemporal_load(iv);
      f32x4 i1 = __builtin_nontemporal_load(iv + 1);
      f32x4 t0 = *reinterpret_cast<const f32x4*>(trow);
      f32x4 t1 = *reinterpret_cast<const f32x4*>(trow + 4);
      acc[0] += s * (t0[0] + i0[0]); acc[1] += s * (t0[1] + i0[1]);
      acc[2] += s * (t0[2] + i0[2]); acc[3] += s * (t0[3] + i0[3]);
      acc[4] += s * (t1[0] + i1[0]); acc[5] += s * (t1[1] + i1[1]);
      acc[6] += s * (t1[2] + i1[2]); acc[7] += s * (t1[3] + i1[3]);
    }
  }
  *reinterpret_cast<uint4*>(agg + (size_t)t * BD_DIM + j) = pack8(acc);
}

// ---- fused MLP: out[M,256] = relu(agg[M,256] x W1T^T + b1) x W2T^T + b2 ----
// One block owns 128 rows; A-chunk (128x256, the FULL contraction) staged to LDS once.
// H is processed in 16 slices of 32:
//   phase A(s): [issue W2-slice-s stage -> Wb[1]] Hs = relu(As x W1_s + b1)   (32 MFMA/wave)
//   phase B(s): [issue W1-slice-(s+1) -> Wb[0]]   oacc += Hs x W2_s           (32 MFMA/wave)
// Stages are issued BEFORE each MFMA phase so the closing __syncthreads vmcnt-drain
// lands after the compute. out (128x256 f32) lives in VGPRs.
// LDS = 64 (As) + 2x16 (Wb) + 10 (Hs) = 106 KiB  -- DELIBERATELY < 128 KiB:
// the round-5 variant with 144 KiB silently failed to launch (out == zeros); 80 KiB
// (round 4) and 128 KiB (m201) are the proven-launchable points on gfx950.
__global__ __launch_bounds__(256, 1) void mlp_fused(
    const uint16_t* __restrict__ A,     // agg, [M][256] bf16
    const uint16_t* __restrict__ W1T,   // [H=512][D=256] bf16
    const uint16_t* __restrict__ W2T,   // [D=256][H=512] bf16
    const float* __restrict__ b1, const float* __restrict__ b2,
    float* __restrict__ Out) {
  __shared__ __align__(16) uint16_t As[128 * 256];      // 64 KB, [kc=0..7][row=0..127][32]
  __shared__ __align__(16) uint16_t Wb[2][SH * 256];    // 2x16 KB; W1: [kc8][hl32][32]; W2: [d256][32]
  __shared__ __align__(16) uint16_t Hs[128 * HS_LD];    // 10 KB, [row][40] (cols 0..31 used)

  const int tid = threadIdx.x;
  const int w = tid >> 6;
  const int l = tid & 63;
  const int lane16 = l & 15;
  const int quad = l >> 4;
  const int m0 = blockIdx.x * 128;

  const int wm  = (w & 1) * 64;       // row offset (both phases)
  const int wnA = (w >> 1) * 16;      // h offset within slice, phase A (out 128x32)
  const int wn2 = (w >> 1) * 128;     // d offset, phase B (out 128x256)

  // ---- stage A-chunk; LDS dest == linear byte off (gload_lds contract), identity layout ----
#pragma unroll
  for (int p = 0; p < 16; ++p) {
    const int off = p * 2048 + tid * 8;          // == kc*4096 + row*32 + c
    const int kc = off >> 12;
    const int row = (off >> 5) & 127;
    const int c = off & 31;
    const uint16_t* g = A + (size_t)(m0 + row) * D_DIM + kc * 32 + c;
    __builtin_amdgcn_global_load_lds((const GLOBAL_AS uint32_t*)g,
                                     (LDS_AS uint32_t*)(As + off), 16, 0, 0);
  }
  // ---- stage W1 slice 0 into Wb[0]: [kc][hl][32], index == off ----
#pragma unroll
  for (int p = 0; p < 4; ++p) {
    const int off = p * 2048 + tid * 8;          // == kc*1024 + hl*32 + c
    const int kc = off >> 10;
    const int hl = (off >> 5) & 31;
    const int c = off & 31;
    const uint16_t* g = W1T + (size_t)hl * D_DIM + kc * 32 + c;   // slice 0: h = hl
    __builtin_amdgcn_global_load_lds((const GLOBAL_AS uint32_t*)g,
                                     (LDS_AS uint32_t*)(Wb[0] + off), 16, 0, 0);
  }
  __syncthreads();

  f32x4 oacc[4][8];
#pragma unroll
  for (int i = 0; i < 4; ++i)
#pragma unroll
    for (int j = 0; j < 8; ++j) oacc[i][j] = (f32x4){0.f, 0.f, 0.f, 0.f};

  for (int s = 0; s < NSLICE; ++s) {
    // ========== phase A(s): Hs = relu(As x W1_s + b1) ==========
    // issue W2 slice s stage into Wb[1]: [d][32], index == off
#pragma unroll
    for (int p = 0; p < 4; ++p) {
      const int off = p * 2048 + tid * 8;        // == d*32 + c
      const int d = off >> 5;
      const int c = off & 31;
      const uint16_t* g = W2T + (size_t)d * H_DIM + s * SH + c;
      __builtin_amdgcn_global_load_lds((const GLOBAL_AS uint32_t*)g,
                                       (LDS_AS uint32_t*)(Wb[1] + off), 16, 0, 0);
    }

    f32x4 hacc[4];
#pragma unroll
    for (int i = 0; i < 4; ++i) hacc[i] = (f32x4){0.f, 0.f, 0.f, 0.f};

#pragma unroll
    for (int kk = 0; kk < 8; ++kk) {
      short8 af[4], bfr;
      bfr = *reinterpret_cast<const short8*>(Wb[0] + kk * 1024 + (wnA + lane16) * 32 + quad * 8);
#pragma unroll
      for (int i = 0; i < 4; ++i)
        af[i] = *reinterpret_cast<const short8*>(As + kk * 4096 + (wm + i * 16 + lane16) * 32 + quad * 8);
#pragma unroll
      for (int i = 0; i < 4; ++i)
        hacc[i] = __builtin_amdgcn_mfma_f32_16x16x32_bf16(af[i], bfr, hacc[i], 0, 0, 0);
    }

    // epilogue: bias+relu, cvt bf16, scatter into Hs[row][hloc]
    {
      const int hloc = wnA + lane16;
      const float bv = b1[s * SH + hloc];
#pragma unroll
      for (int i = 0; i < 4; ++i) {
#pragma unroll
        for (int r = 0; r < 4; ++r) {
          const int row = wm + i * 16 + quad * 4 + r;
          const float x = fmaxf(hacc[i][r] + bv, 0.f);
          Hs[row * HS_LD + hloc] = (uint16_t)f2bf_rne(x);
        }
      }
    }
    __syncthreads();   // Hs visible; W2 slice s resident; Wb[0] free

    // ========== phase B(s): oacc += Hs x W2_s ==========
    if (s < NSLICE - 1) {
#pragma unroll
      for (int p = 0; p < 4; ++p) {
        const int off = p * 2048 + tid * 8;
        const int kc = off >> 10;
        const int hl = (off >> 5) & 31;
        const int c = off & 31;
        const uint16_t* g = W1T + (size_t)((s + 1) * SH + hl) * D_DIM + kc * 32 + c;
        __builtin_amdgcn_global_load_lds((const GLOBAL_AS uint32_t*)g,
                                         (LDS_AS uint32_t*)(Wb[0] + off), 16, 0, 0);
      }
    }

    {
      short8 af2[4], bf2[8];
#pragma unroll
      for (int i = 0; i < 4; ++i)
        af2[i] = *reinterpret_cast<const short8*>(Hs + (wm + i * 16 + lane16) * HS_LD + quad * 8);
#pragma unroll
      for (int j = 0; j < 8; ++j)
        bf2[j] = *reinterpret_cast<const short8*>(Wb[1] + (wn2 + j * 16 + lane16) * 32 + quad * 8);
#pragma unroll
      for (int i = 0; i < 4; ++i)
#pragma unroll
        for (int j = 0; j < 8; ++j)
          oacc[i][j] = __builtin_amdgcn_mfma_f32_16x16x32_bf16(af2[i], bf2[j], oacc[i][j], 0, 0, 0);
    }
    __syncthreads();   // Hs/Wb[1] free; W1 slice s+1 resident
  }

  // ---- final epilogue: out = oacc + b2 (f32, coalesced dword stores) ----
#pragma unroll
  for (int j = 0; j < 8; ++j) {
    const int col = wn2 + j * 16 + lane16;
    const float bv = b2[col];
#pragma unroll
    for (int i = 0; i < 4; ++i) {
#pragma unroll
      for (int r = 0; r < 4; ++r) {
        const int row = m0 + wm + i * 16 + quad * 4 + r;
        Out[(size_t)row * D_DIM + col] = oacc[i][j][r] + bv;
      }
    }
  }
}

extern "C" void kernel_launch(void* const* d_in, const int* in_sizes, int n_in,
                              void* d_out, int out_size, void* d_ws, size_t ws_size,
                              hipStream_t stream) {
  const float* term  = (const float*)d_in[0];
  const float* pred  = (const float*)d_in[1];
  const float* inv   = (const float*)d_in[2];
  const float* signs = (const float*)d_in[3];
  const float* W1    = (const float*)d_in[4];
  const float* b1    = (const float*)d_in[5];
  const float* W2    = (const float*)d_in[6];
  const float* b2    = (const float*)d_in[7];
  const int* heads   = (const int*)d_in[8];
  const int* tails   = (const int*)d_in[9];

  char* ws = (char*)d_ws;
  uint16_t* W1T = (uint16_t*)(ws);              // 512*256*2 = 256 KB
  uint16_t* W2T = (uint16_t*)(ws + 262144);     // 256*512*2 = 256 KB
  uint16_t* agg = (uint16_t*)(ws + 524288);     // 65536*256*2 = 32 MB

  // dispatch 1: agg (y<16) + weight prep (y==16)
  agg_prep_kernel<<<dim3(BD_DIM / 8 / 256, T_DIM + 1), dim3(256), 0, stream>>>(
      term, pred, inv, signs, heads, tails, W1, W2, agg, W1T, W2T);
  // dispatch 2: fused MLP
  mlp_fused<<<dim3(M_DIM / 128), dim3(256), 0, stream>>>(
      agg, W1T, W2T, b1, b2, (float*)d_out);
}

// Round 7
// 413.947 us; speedup vs baseline: 1.0400x; 1.0364x over previous
//
#include <hip/hip_runtime.h>
#include <hip/hip_bf16.h>
#include <stdint.h>

#define T_DIM 16
#define B_DIM 4096
#define D_DIM 256
#define H_DIM 512
#define E_DIM 32
#define M_DIM (T_DIM * B_DIM)      // 65536 rows for the GEMMs
#define BD_DIM (B_DIM * D_DIM)     // 1048576 elems per t-slice
#define EPS_F 0.1f

#define NSLICE 16                  // H / SH
#define SH 32                      // h-columns per slice
#define HS_LD 40                   // Hs leading dim (pad 32->40: 16B-aligned b128, bank-spread)

typedef __attribute__((ext_vector_type(8))) short short8;   // 8 bf16 = 4 VGPRs (MFMA A/B frag)
typedef __attribute__((ext_vector_type(4))) float f32x4;    // MFMA C/D frag; clang vec (nontemporal ok)

#define GLOBAL_AS __attribute__((address_space(1)))
#define LDS_AS __attribute__((address_space(3)))

__device__ __forceinline__ uint32_t f2bf_rne(float x) {
  uint32_t u = __float_as_uint(x);
  return (u + 0x7fffu + ((u >> 16) & 1u)) >> 16;
}

__device__ __forceinline__ uint4 pack8(const float* f) {
  uint4 v;
  v.x = f2bf_rne(f[0]) | (f2bf_rne(f[1]) << 16);
  v.y = f2bf_rne(f[2]) | (f2bf_rne(f[3]) << 16);
  v.z = f2bf_rne(f[4]) | (f2bf_rne(f[5]) << 16);
  v.w = f2bf_rne(f[6]) | (f2bf_rne(f[7]) << 16);
  return v;
}

// ---- agg+prep combined: blockIdx.y < 16 -> agg t-slice; blockIdx.y == 16 -> weight prep ----
// agg path: proven round-2 kernel; three structural variants all plateau at ~2.6-2.7 TB/s
// (latency chains ruled out by round-3 list variant) -> treated as at its pattern floor.
__global__ __launch_bounds__(256) void agg_prep_kernel(
    const float* __restrict__ term, const float* __restrict__ pred,
    const float* __restrict__ inv, const float* __restrict__ signs,
    const int* __restrict__ heads, const int* __restrict__ tails,
    const float* __restrict__ W1, const float* __restrict__ W2,
    uint16_t* __restrict__ agg, uint16_t* __restrict__ W1T, uint16_t* __restrict__ W2T) {
  if (blockIdx.y == T_DIM) {  // ---- prep path: transpose+cvt both weight matrices ----
    const int idx = blockIdx.x * 256 + threadIdx.x;     // 0 .. 131071 == D*H
    const int d = idx >> 9, h = idx & (H_DIM - 1);      // idx = d*H + h
    W1T[h * D_DIM + d] = (uint16_t)f2bf_rne(W1[idx]);   // W1T[h][d] = W1[d][h]
    const int h2 = idx >> 8, d2 = idx & (D_DIM - 1);    // idx = h2*D + d2
    W2T[d2 * H_DIM + h2] = (uint16_t)f2bf_rne(W2[idx]); // W2T[d][h] = W2[h][d]
    return;
  }

  __shared__ int sh_h[E_DIM], sh_t[E_DIM];
  __shared__ float sh_s[E_DIM];
  if (threadIdx.x < E_DIM) {
    int e = threadIdx.x;
    sh_h[e] = heads[e] & (T_DIM - 1);   // defensive clamp, values are 0..15
    sh_t[e] = tails[e] & (T_DIM - 1);
    sh_s[e] = signs[e];
  }
  __syncthreads();

  const int t = blockIdx.y;                            // one t-slice per block row
  const int j = (blockIdx.x * 256 + threadIdx.x) * 8;  // elem offset in [0, B*D)

  float acc[8];
  {
    f32x4 a = *reinterpret_cast<const f32x4*>(term + (size_t)t * BD_DIM + j);
    f32x4 b = *reinterpret_cast<const f32x4*>(term + (size_t)t * BD_DIM + j + 4);
    acc[0] = EPS_F * a[0]; acc[1] = EPS_F * a[1]; acc[2] = EPS_F * a[2]; acc[3] = EPS_F * a[3];
    acc[4] = EPS_F * b[0]; acc[5] = EPS_F * b[1]; acc[6] = EPS_F * b[2]; acc[7] = EPS_F * b[3];
  }

#pragma unroll 1
  for (int e = 0; e < E_DIM; ++e) {
    const float s = sh_s[e];
    if (sh_t[e] == t) {   // wave-uniform branch
      const f32x4* p = reinterpret_cast<const f32x4*>(pred + (size_t)e * BD_DIM + j);
      const float* hrow = term + (size_t)sh_h[e] * BD_DIM + j;
      f32x4 p0 = __builtin_nontemporal_load(p);
      f32x4 p1 = __builtin_nontemporal_load(p + 1);
      f32x4 h0 = *reinterpret_cast<const f32x4*>(hrow);
      f32x4 h1 = *reinterpret_cast<const f32x4*>(hrow + 4);
      acc[0] += s * (h0[0] + p0[0]); acc[1] += s * (h0[1] + p0[1]);
      acc[2] += s * (h0[2] + p0[2]); acc[3] += s * (h0[3] + p0[3]);
      acc[4] += s * (h1[0] + p1[0]); acc[5] += s * (h1[1] + p1[1]);
      acc[6] += s * (h1[2] + p1[2]); acc[7] += s * (h1[3] + p1[3]);
    }
    if (sh_h[e] == t) {   // wave-uniform branch
      const f32x4* iv = reinterpret_cast<const f32x4*>(inv + (size_t)e * BD_DIM + j);
      const float* trow = term + (size_t)sh_t[e] * BD_DIM + j;
      f32x4 i0 = __builtin_nontemporal_load(iv);
      f32x4 i1 = __builtin_nontemporal_load(iv + 1);
      f32x4 t0 = *reinterpret_cast<const f32x4*>(trow);
      f32x4 t1 = *reinterpret_cast<const f32x4*>(trow + 4);
      acc[0] += s * (t0[0] + i0[0]); acc[1] += s * (t0[1] + i0[1]);
      acc[2] += s * (t0[2] + i0[2]); acc[3] += s * (t0[3] + i0[3]);
      acc[4] += s * (t1[0] + i1[0]); acc[5] += s * (t1[1] + i1[1]);
      acc[6] += s * (t1[2] + i1[2]); acc[7] += s * (t1[3] + i1[3]);
    }
  }
  *reinterpret_cast<uint4*>(agg + (size_t)t * BD_DIM + j) = pack8(acc);
}

// ---- fused MLP v2: out[M,256] = relu(agg[M,256] x W1T^T + b1) x W2T^T + b2 ----
// Round-6 structure (verified correct), row tile halved 128->64 so LDS = 32 (As) +
// 2x16 (Wb dbuf) + 5 (Hs) = 69 KB -> 2 blocks/CU (8 waves/CU): each block's barrier
// and vmcnt drains now overlap with the OTHER block's MFMA phases (round 6 ran
// 1 block/CU = 4 waves, nothing to overlap with).
// Per slice s (16 slices of SH=32 h-cols):
//   phase A(s): [issue W2-slice-s -> Wb[1]] Hs = relu(As x W1_s + b1)   (16 MFMA/wave)
//   phase B(s): [issue W1-slice-(s+1) -> Wb[0]] oacc += Hs x W2_s       (16 MFMA/wave)
__global__ __launch_bounds__(256, 2) void mlp_fused(
    const uint16_t* __restrict__ A,     // agg, [M][256] bf16
    const uint16_t* __restrict__ W1T,   // [H=512][D=256] bf16
    const uint16_t* __restrict__ W2T,   // [D=256][H=512] bf16
    const float* __restrict__ b1, const float* __restrict__ b2,
    float* __restrict__ Out) {
  __shared__ __align__(16) uint16_t As[64 * 256];       // 32 KB, [kc=0..7][row=0..63][32]
  __shared__ __align__(16) uint16_t Wb[2][SH * 256];    // 2x16 KB; W1: [kc8][hl32][32]; W2: [d256][32]
  __shared__ __align__(16) uint16_t Hs[64 * HS_LD];     // 5 KB, [row][40] (cols 0..31 used)

  const int tid = threadIdx.x;
  const int w = tid >> 6;
  const int l = tid & 63;
  const int lane16 = l & 15;
  const int quad = l >> 4;
  const int m0 = blockIdx.x * 64;

  const int wm  = (w & 1) * 32;           // row offset (both phases), 2-way
  const int wnA = ((w >> 1) & 1) * 16;    // h offset within slice, phase A (out 64x32)
  const int wn2 = ((w >> 1) & 1) * 128;   // d offset, phase B (out 64x256)

  // ---- stage A-chunk (8 passes); LDS dest == linear byte off (gload_lds contract) ----
#pragma unroll
  for (int p = 0; p < 8; ++p) {
    const int off = p * 2048 + tid * 8;          // == kc*2048 + row*32 + c
    const int kc = off >> 11;
    const int row = (off >> 5) & 63;
    const int c = off & 31;
    const uint16_t* g = A + (size_t)(m0 + row) * D_DIM + kc * 32 + c;
    __builtin_amdgcn_global_load_lds((const GLOBAL_AS uint32_t*)g,
                                     (LDS_AS uint32_t*)(As + off), 16, 0, 0);
  }
  // ---- stage W1 slice 0 into Wb[0]: [kc][hl][32], index == off ----
#pragma unroll
  for (int p = 0; p < 4; ++p) {
    const int off = p * 2048 + tid * 8;          // == kc*1024 + hl*32 + c
    const int kc = off >> 10;
    const int hl = (off >> 5) & 31;
    const int c = off & 31;
    const uint16_t* g = W1T + (size_t)hl * D_DIM + kc * 32 + c;   // slice 0: h = hl
    __builtin_amdgcn_global_load_lds((const GLOBAL_AS uint32_t*)g,
                                     (LDS_AS uint32_t*)(Wb[0] + off), 16, 0, 0);
  }
  __syncthreads();

  f32x4 oacc[2][8];
#pragma unroll
  for (int i = 0; i < 2; ++i)
#pragma unroll
    for (int j = 0; j < 8; ++j) oacc[i][j] = (f32x4){0.f, 0.f, 0.f, 0.f};

  for (int s = 0; s < NSLICE; ++s) {
    // ========== phase A(s): Hs = relu(As x W1_s + b1) ==========
    // issue W2 slice s stage into Wb[1]: [d][32], index == off
#pragma unroll
    for (int p = 0; p < 4; ++p) {
      const int off = p * 2048 + tid * 8;        // == d*32 + c
      const int d = off >> 5;
      const int c = off & 31;
      const uint16_t* g = W2T + (size_t)d * H_DIM + s * SH + c;
      __builtin_amdgcn_global_load_lds((const GLOBAL_AS uint32_t*)g,
                                       (LDS_AS uint32_t*)(Wb[1] + off), 16, 0, 0);
    }

    f32x4 hacc[2];
#pragma unroll
    for (int i = 0; i < 2; ++i) hacc[i] = (f32x4){0.f, 0.f, 0.f, 0.f};

#pragma unroll
    for (int kk = 0; kk < 8; ++kk) {
      short8 af[2], bfr;
      bfr = *reinterpret_cast<const short8*>(Wb[0] + kk * 1024 + (wnA + lane16) * 32 + quad * 8);
#pragma unroll
      for (int i = 0; i < 2; ++i)
        af[i] = *reinterpret_cast<const short8*>(As + kk * 2048 + (wm + i * 16 + lane16) * 32 + quad * 8);
#pragma unroll
      for (int i = 0; i < 2; ++i)
        hacc[i] = __builtin_amdgcn_mfma_f32_16x16x32_bf16(af[i], bfr, hacc[i], 0, 0, 0);
    }

    // epilogue: bias+relu, cvt bf16, scatter into Hs[row][hloc]
    {
      const int hloc = wnA + lane16;
      const float bv = b1[s * SH + hloc];
#pragma unroll
      for (int i = 0; i < 2; ++i) {
#pragma unroll
        for (int r = 0; r < 4; ++r) {
          const int row = wm + i * 16 + quad * 4 + r;
          const float x = fmaxf(hacc[i][r] + bv, 0.f);
          Hs[row * HS_LD + hloc] = (uint16_t)f2bf_rne(x);
        }
      }
    }
    __syncthreads();   // Hs visible; W2 slice s resident; Wb[0] free

    // ========== phase B(s): oacc += Hs x W2_s ==========
    if (s < NSLICE - 1) {
#pragma unroll
      for (int p = 0; p < 4; ++p) {
        const int off = p * 2048 + tid * 8;
        const int kc = off >> 10;
        const int hl = (off >> 5) & 31;
        const int c = off & 31;
        const uint16_t* g = W1T + (size_t)((s + 1) * SH + hl) * D_DIM + kc * 32 + c;
        __builtin_amdgcn_global_load_lds((const GLOBAL_AS uint32_t*)g,
                                         (LDS_AS uint32_t*)(Wb[0] + off), 16, 0, 0);
      }
    }

    {
      short8 af2[2], bf2[8];
#pragma unroll
      for (int i = 0; i < 2; ++i)
        af2[i] = *reinterpret_cast<const short8*>(Hs + (wm + i * 16 + lane16) * HS_LD + quad * 8);
#pragma unroll
      for (int j = 0; j < 8; ++j)
        bf2[j] = *reinterpret_cast<const short8*>(Wb[1] + (wn2 + j * 16 + lane16) * 32 + quad * 8);
#pragma unroll
      for (int i = 0; i < 2; ++i)
#pragma unroll
        for (int j = 0; j < 8; ++j)
          oacc[i][j] = __builtin_amdgcn_mfma_f32_16x16x32_bf16(af2[i], bf2[j], oacc[i][j], 0, 0, 0);
    }
    __syncthreads();   // Hs/Wb[1] free; W1 slice s+1 resident
  }

  // ---- final epilogue: out = oacc + b2 (f32, coalesced dword stores) ----
#pragma unroll
  for (int j = 0; j < 8; ++j) {
    const int col = wn2 + j * 16 + lane16;
    const float bv = b2[col];
#pragma unroll
    for (int i = 0; i < 2; ++i) {
#pragma unroll
      for (int r = 0; r < 4; ++r) {
        const int row = m0 + wm + i * 16 + quad * 4 + r;
        Out[(size_t)row * D_DIM + col] = oacc[i][j][r] + bv;
      }
    }
  }
}

extern "C" void kernel_launch(void* const* d_in, const int* in_sizes, int n_in,
                              void* d_out, int out_size, void* d_ws, size_t ws_size,
                              hipStream_t stream) {
  const float* term  = (const float*)d_in[0];
  const float* pred  = (const float*)d_in[1];
  const float* inv   = (const float*)d_in[2];
  const float* signs = (const float*)d_in[3];
  const float* W1    = (const float*)d_in[4];
  const float* b1    = (const float*)d_in[5];
  const float* W2    = (const float*)d_in[6];
  const float* b2    = (const float*)d_in[7];
  const int* heads   = (const int*)d_in[8];
  const int* tails   = (const int*)d_in[9];

  char* ws = (char*)d_ws;
  uint16_t* W1T = (uint16_t*)(ws);              // 512*256*2 = 256 KB
  uint16_t* W2T = (uint16_t*)(ws + 262144);     // 256*512*2 = 256 KB
  uint16_t* agg = (uint16_t*)(ws + 524288);     // 65536*256*2 = 32 MB

  // dispatch 1: agg (y<16) + weight prep (y==16)
  agg_prep_kernel<<<dim3(BD_DIM / 8 / 256, T_DIM + 1), dim3(256), 0, stream>>>(
      term, pred, inv, signs, heads, tails, W1, W2, agg, W1T, W2T);
  // dispatch 2: fused MLP (64-row tiles, 2 blocks/CU)
  mlp_fused<<<dim3(M_DIM / 64), dim3(256), 0, stream>>>(
      agg, W1T, W2T, b1, b2, (float*)d_out);
}

// Round 8
// 399.333 us; speedup vs baseline: 1.0781x; 1.0366x over previous
//
#include <hip/hip_runtime.h>
#include <hip/hip_bf16.h>
#include <stdint.h>

#define T_DIM 16
#define B_DIM 4096
#define D_DIM 256
#define H_DIM 512
#define E_DIM 32
#define M_DIM (T_DIM * B_DIM)      // 65536 rows for the GEMMs
#define BD_DIM (B_DIM * D_DIM)     // 1048576 elems per t-slice
#define EPS_F 0.1f

#define NSLICE 16                  // H / SH
#define SH 32                      // h-columns per slice
#define HS_LD 40                   // Hs leading dim (pad 32->40: 16B-aligned b128, bank-spread)
#define MAXS 64                    // worst case: all 64 stream entries on one t

typedef __attribute__((ext_vector_type(8))) short short8;   // 8 bf16 = 4 VGPRs (MFMA A/B frag)
typedef __attribute__((ext_vector_type(4))) float f32x4;    // MFMA C/D frag; clang vec (nontemporal ok)

#define GLOBAL_AS __attribute__((address_space(1)))
#define LDS_AS __attribute__((address_space(3)))

__device__ __forceinline__ uint32_t f2bf_rne(float x) {
  uint32_t u = __float_as_uint(x);
  return (u + 0x7fffu + ((u >> 16) & 1u)) >> 16;
}

__device__ __forceinline__ uint4 pack8(const float* f) {
  uint4 v;
  v.x = f2bf_rne(f[0]) | (f2bf_rne(f[1]) << 16);
  v.y = f2bf_rne(f[2]) | (f2bf_rne(f[3]) << 16);
  v.z = f2bf_rne(f[4]) | (f2bf_rne(f[5]) << 16);
  v.w = f2bf_rne(f[6]) | (f2bf_rne(f[7]) << 16);
  return v;
}

// ---- agg v4 (register-resident term) + prep, one dispatch ----
// Roofline insight (rounds 2/3/7): agg's TOTAL vector-memory traffic (608 MB incl.
// L3-served term re-reads) ran at 6.0-6.2 TB/s == the 6.3 TB/s chip ceiling. So cut
// traffic: load all 16 term slices for this j-chunk into REGISTERS once (128 VGPR),
// fold the term-gather into a static 16x16 combine agg[t] = sum_s C[t][s]*term_reg[s]
// (C = EPS*I + sign scatter; static unroll avoids runtime reg indexing), then walk
// per-t stream lists for pred/inv (dynamic POINTERS are fine). 352 MB total.
// blockIdx.x >= 512 -> weight-prep path (rides along, free).
__global__ __launch_bounds__(256, 2) void agg_prep_kernel(
    const float* __restrict__ term, const float* __restrict__ pred,
    const float* __restrict__ inv, const float* __restrict__ signs,
    const int* __restrict__ heads, const int* __restrict__ tails,
    const float* __restrict__ W1, const float* __restrict__ W2,
    uint16_t* __restrict__ agg, uint16_t* __restrict__ W1T, uint16_t* __restrict__ W2T) {
  const int tid = threadIdx.x;
  if (blockIdx.x >= 512) {  // ---- prep path: transpose+cvt both weight matrices ----
    const int idx = (blockIdx.x - 512) * 256 + tid;     // 0 .. 131071 == D*H
    const int d = idx >> 9, h = idx & (H_DIM - 1);      // idx = d*H + h
    W1T[h * D_DIM + d] = (uint16_t)f2bf_rne(W1[idx]);   // W1T[h][d] = W1[d][h]
    const int h2 = idx >> 8, d2 = idx & (D_DIM - 1);    // idx = h2*D + d2
    W2T[d2 * H_DIM + h2] = (uint16_t)f2bf_rne(W2[idx]); // W2T[d][h] = W2[h][d]
    return;
  }

  __shared__ float Cm[T_DIM][T_DIM];      // combine matrix (row t, col s)
  __shared__ float Lsgn[T_DIM][MAXS];     // per-t stream signs
  __shared__ uint64_t Lptr[T_DIM][MAXS];  // per-t stream base ptrs (pred/inv + e*BD)
  __shared__ int Lcnt[T_DIM];

  Cm[tid >> 4][tid & 15] = ((tid >> 4) == (tid & 15)) ? EPS_F : 0.f;
  if (tid < T_DIM) Lcnt[tid] = 0;
  __syncthreads();
  if (tid < E_DIM) {   // parallel build; list order is irrelevant (sum)
    const int e = tid;
    const int hh = heads[e] & (T_DIM - 1);   // defensive clamp, values are 0..15
    const int tt = tails[e] & (T_DIM - 1);
    const float s = signs[e];
    atomicAdd(&Cm[tt][hh], s);               // tail gets s*term[head]
    int i = atomicAdd(&Lcnt[tt], 1);
    Lsgn[tt][i] = s; Lptr[tt][i] = (uint64_t)(pred + (size_t)e * BD_DIM);
    atomicAdd(&Cm[hh][tt], s);               // head gets s*term[tail]
    i = atomicAdd(&Lcnt[hh], 1);
    Lsgn[hh][i] = s; Lptr[hh][i] = (uint64_t)(inv + (size_t)e * BD_DIM);
  }
  __syncthreads();

  const int j = (blockIdx.x * 256 + tid) * 8;  // elem offset in [0, B*D)

  // ---- all 16 term slices for this j-chunk -> registers (read once, nt) ----
  f32x4 ta[T_DIM], tb[T_DIM];
#pragma unroll
  for (int s = 0; s < T_DIM; ++s) {
    ta[s] = __builtin_nontemporal_load(reinterpret_cast<const f32x4*>(term + (size_t)s * BD_DIM + j));
    tb[s] = __builtin_nontemporal_load(reinterpret_cast<const f32x4*>(term + (size_t)s * BD_DIM + j + 4));
  }

#pragma unroll 1
  for (int t = 0; t < T_DIM; ++t) {
    f32x4 cv[4];   // C row t as 4 vectors; cv[s>>2][s&3] is static under full unroll
#pragma unroll
    for (int q = 0; q < 4; ++q)
      cv[q] = *reinterpret_cast<const f32x4*>(&Cm[t][q * 4]);

    float acc[8];
#pragma unroll
    for (int k = 0; k < 8; ++k) acc[k] = 0.f;

#pragma unroll
    for (int s = 0; s < T_DIM; ++s) {
      const float cs = cv[s >> 2][s & 3];
#pragma unroll
      for (int k = 0; k < 4; ++k) {
        acc[k]     += cs * ta[s][k];
        acc[k + 4] += cs * tb[s][k];
      }
    }

    const int n = Lcnt[t];
#pragma unroll 2
    for (int i = 0; i < n; ++i) {
      const float sg = Lsgn[t][i];
      const float* bp = (const float*)Lptr[t][i];
      f32x4 p0 = __builtin_nontemporal_load(reinterpret_cast<const f32x4*>(bp + j));
      f32x4 p1 = __builtin_nontemporal_load(reinterpret_cast<const f32x4*>(bp + j + 4));
#pragma unroll
      for (int k = 0; k < 4; ++k) {
        acc[k]     += sg * p0[k];
        acc[k + 4] += sg * p1[k];
      }
    }
    *reinterpret_cast<uint4*>(agg + (size_t)t * BD_DIM + j) = pack8(acc);
  }
}

// ---- fused MLP v2 (round-7 verified, byte-identical) ----
// out[M,256] = relu(agg[M,256] x W1T^T + b1) x W2T^T + b2; 64-row tiles, 2 blocks/CU.
__global__ __launch_bounds__(256, 2) void mlp_fused(
    const uint16_t* __restrict__ A,     // agg, [M][256] bf16
    const uint16_t* __restrict__ W1T,   // [H=512][D=256] bf16
    const uint16_t* __restrict__ W2T,   // [D=256][H=512] bf16
    const float* __restrict__ b1, const float* __restrict__ b2,
    float* __restrict__ Out) {
  __shared__ __align__(16) uint16_t As[64 * 256];       // 32 KB, [kc=0..7][row=0..63][32]
  __shared__ __align__(16) uint16_t Wb[2][SH * 256];    // 2x16 KB; W1: [kc8][hl32][32]; W2: [d256][32]
  __shared__ __align__(16) uint16_t Hs[64 * HS_LD];     // 5 KB, [row][40] (cols 0..31 used)

  const int tid = threadIdx.x;
  const int w = tid >> 6;
  const int l = tid & 63;
  const int lane16 = l & 15;
  const int quad = l >> 4;
  const int m0 = blockIdx.x * 64;

  const int wm  = (w & 1) * 32;           // row offset (both phases), 2-way
  const int wnA = ((w >> 1) & 1) * 16;    // h offset within slice, phase A (out 64x32)
  const int wn2 = ((w >> 1) & 1) * 128;   // d offset, phase B (out 64x256)

  // ---- stage A-chunk (8 passes); LDS dest == linear byte off (gload_lds contract) ----
#pragma unroll
  for (int p = 0; p < 8; ++p) {
    const int off = p * 2048 + tid * 8;          // == kc*2048 + row*32 + c
    const int kc = off >> 11;
    const int row = (off >> 5) & 63;
    const int c = off & 31;
    const uint16_t* g = A + (size_t)(m0 + row) * D_DIM + kc * 32 + c;
    __builtin_amdgcn_global_load_lds((const GLOBAL_AS uint32_t*)g,
                                     (LDS_AS uint32_t*)(As + off), 16, 0, 0);
  }
  // ---- stage W1 slice 0 into Wb[0]: [kc][hl][32], index == off ----
#pragma unroll
  for (int p = 0; p < 4; ++p) {
    const int off = p * 2048 + tid * 8;          // == kc*1024 + hl*32 + c
    const int kc = off >> 10;
    const int hl = (off >> 5) & 31;
    const int c = off & 31;
    const uint16_t* g = W1T + (size_t)hl * D_DIM + kc * 32 + c;   // slice 0: h = hl
    __builtin_amdgcn_global_load_lds((const GLOBAL_AS uint32_t*)g,
                                     (LDS_AS uint32_t*)(Wb[0] + off), 16, 0, 0);
  }
  __syncthreads();

  f32x4 oacc[2][8];
#pragma unroll
  for (int i = 0; i < 2; ++i)
#pragma unroll
    for (int j = 0; j < 8; ++j) oacc[i][j] = (f32x4){0.f, 0.f, 0.f, 0.f};

  for (int s = 0; s < NSLICE; ++s) {
    // ========== phase A(s): Hs = relu(As x W1_s + b1) ==========
    // issue W2 slice s stage into Wb[1]: [d][32], index == off
#pragma unroll
    for (int p = 0; p < 4; ++p) {
      const int off = p * 2048 + tid * 8;        // == d*32 + c
      const int d = off >> 5;
      const int c = off & 31;
      const uint16_t* g = W2T + (size_t)d * H_DIM + s * SH + c;
      __builtin_amdgcn_global_load_lds((const GLOBAL_AS uint32_t*)g,
                                       (LDS_AS uint32_t*)(Wb[1] + off), 16, 0, 0);
    }

    f32x4 hacc[2];
#pragma unroll
    for (int i = 0; i < 2; ++i) hacc[i] = (f32x4){0.f, 0.f, 0.f, 0.f};

#pragma unroll
    for (int kk = 0; kk < 8; ++kk) {
      short8 af[2], bfr;
      bfr = *reinterpret_cast<const short8*>(Wb[0] + kk * 1024 + (wnA + lane16) * 32 + quad * 8);
#pragma unroll
      for (int i = 0; i < 2; ++i)
        af[i] = *reinterpret_cast<const short8*>(As + kk * 2048 + (wm + i * 16 + lane16) * 32 + quad * 8);
#pragma unroll
      for (int i = 0; i < 2; ++i)
        hacc[i] = __builtin_amdgcn_mfma_f32_16x16x32_bf16(af[i], bfr, hacc[i], 0, 0, 0);
    }

    // epilogue: bias+relu, cvt bf16, scatter into Hs[row][hloc]
    {
      const int hloc = wnA + lane16;
      const float bv = b1[s * SH + hloc];
#pragma unroll
      for (int i = 0; i < 2; ++i) {
#pragma unroll
        for (int r = 0; r < 4; ++r) {
          const int row = wm + i * 16 + quad * 4 + r;
          const float x = fmaxf(hacc[i][r] + bv, 0.f);
          Hs[row * HS_LD + hloc] = (uint16_t)f2bf_rne(x);
        }
      }
    }
    __syncthreads();   // Hs visible; W2 slice s resident; Wb[0] free

    // ========== phase B(s): oacc += Hs x W2_s ==========
    if (s < NSLICE - 1) {
#pragma unroll
      for (int p = 0; p < 4; ++p) {
        const int off = p * 2048 + tid * 8;
        const int kc = off >> 10;
        const int hl = (off >> 5) & 31;
        const int c = off & 31;
        const uint16_t* g = W1T + (size_t)((s + 1) * SH + hl) * D_DIM + kc * 32 + c;
        __builtin_amdgcn_global_load_lds((const GLOBAL_AS uint32_t*)g,
                                         (LDS_AS uint32_t*)(Wb[0] + off), 16, 0, 0);
      }
    }

    {
      short8 af2[2], bf2[8];
#pragma unroll
      for (int i = 0; i < 2; ++i)
        af2[i] = *reinterpret_cast<const short8*>(Hs + (wm + i * 16 + lane16) * HS_LD + quad * 8);
#pragma unroll
      for (int j = 0; j < 8; ++j)
        bf2[j] = *reinterpret_cast<const short8*>(Wb[1] + (wn2 + j * 16 + lane16) * 32 + quad * 8);
#pragma unroll
      for (int i = 0; i < 2; ++i)
#pragma unroll
        for (int j = 0; j < 8; ++j)
          oacc[i][j] = __builtin_amdgcn_mfma_f32_16x16x32_bf16(af2[i], bf2[j], oacc[i][j], 0, 0, 0);
    }
    __syncthreads();   // Hs/Wb[1] free; W1 slice s+1 resident
  }

  // ---- final epilogue: out = oacc + b2 (f32, coalesced dword stores) ----
#pragma unroll
  for (int j = 0; j < 8; ++j) {
    const int col = wn2 + j * 16 + lane16;
    const float bv = b2[col];
#pragma unroll
    for (int i = 0; i < 2; ++i) {
#pragma unroll
      for (int r = 0; r < 4; ++r) {
        const int row = m0 + wm + i * 16 + quad * 4 + r;
        Out[(size_t)row * D_DIM + col] = oacc[i][j][r] + bv;
      }
    }
  }
}

extern "C" void kernel_launch(void* const* d_in, const int* in_sizes, int n_in,
                              void* d_out, int out_size, void* d_ws, size_t ws_size,
                              hipStream_t stream) {
  const float* term  = (const float*)d_in[0];
  const float* pred  = (const float*)d_in[1];
  const float* inv   = (const float*)d_in[2];
  const float* signs = (const float*)d_in[3];
  const float* W1    = (const float*)d_in[4];
  const float* b1    = (const float*)d_in[5];
  const float* W2    = (const float*)d_in[6];
  const float* b2    = (const float*)d_in[7];
  const int* heads   = (const int*)d_in[8];
  const int* tails   = (const int*)d_in[9];

  char* ws = (char*)d_ws;
  uint16_t* W1T = (uint16_t*)(ws);              // 512*256*2 = 256 KB
  uint16_t* W2T = (uint16_t*)(ws + 262144);     // 256*512*2 = 256 KB
  uint16_t* agg = (uint16_t*)(ws + 524288);     // 65536*256*2 = 32 MB

  // dispatch 1: agg v4 (blocks 0..511, one j-chunk each, all 16 t) + prep (blocks 512..1023)
  agg_prep_kernel<<<dim3(1024), dim3(256), 0, stream>>>(
      term, pred, inv, signs, heads, tails, W1, W2, agg, W1T, W2T);
  // dispatch 2: fused MLP (64-row tiles, 2 blocks/CU)
  mlp_fused<<<dim3(M_DIM / 64), dim3(256), 0, stream>>>(
      agg, W1T, W2T, b1, b2, (float*)d_out);
}

// Round 9
// 392.613 us; speedup vs baseline: 1.0965x; 1.0171x over previous
//
#include <hip/hip_runtime.h>
#include <hip/hip_bf16.h>
#include <stdint.h>

#define T_DIM 16
#define B_DIM 4096
#define D_DIM 256
#define H_DIM 512
#define E_DIM 32
#define M_DIM (T_DIM * B_DIM)
#define BD_DIM (B_DIM * D_DIM)     // elems per term/pred slice
#define EPS_F 0.1f

#define NSLICE 16                  // H / SH
#define SH 32                      // h-columns per slice
#define HS_LD 40                   // Hs leading dim (pad 32->40: 16B-aligned b128, bank-spread)

typedef __attribute__((ext_vector_type(8))) short short8;   // 8 bf16 (MFMA A/B frag)
typedef __attribute__((ext_vector_type(4))) float f32x4;    // MFMA C/D frag; clang vec (nontemporal ok)

#define GLOBAL_AS __attribute__((address_space(1)))
#define LDS_AS __attribute__((address_space(3)))

__device__ __forceinline__ uint32_t f2bf_rne(float x) {
  uint32_t u = __float_as_uint(x);
  return (u + 0x7fffu + ((u >> 16) & 1u)) >> 16;
}

// ---- prep: f32 W1 (DxH) -> bf16 W1T (HxD); f32 W2 (HxD) -> bf16 W2T (DxH) ----
__global__ __launch_bounds__(256) void prep_kernel(
    const float* __restrict__ W1, const float* __restrict__ W2,
    uint16_t* __restrict__ W1T, uint16_t* __restrict__ W2T) {
  const int idx = blockIdx.x * 256 + threadIdx.x;     // 0 .. 131071 == D*H
  const int d = idx >> 9, h = idx & (H_DIM - 1);
  W1T[h * D_DIM + d] = (uint16_t)f2bf_rne(W1[idx]);
  const int h2 = idx >> 8, d2 = idx & (D_DIM - 1);
  W2T[d2 * H_DIM + h2] = (uint16_t)f2bf_rne(W2[idx]);
}

// ---- fully fused: agg (per-b local) + 2-layer MLP, one kernel ----
// Block owns 4 b-columns => A-tile = 64 rows (4b x 16t) x 256, built IN LDS by the agg
// phase (no 32MB agg round-trip). Then the round-7-verified slice loop runs on it.
// agg math = round-8-verified register-resident-term scheme (C = EPS*I + sign scatter,
// per-t stream lists), with 4-elem chunks (64 term VGPRs).
// LDS: As 32K + Wb 2x16K + Hs 5K + lists ~5.3K = ~74.2 KB -> 2 blocks/CU.
__global__ __launch_bounds__(256, 2) void fused_all(
    const float* __restrict__ term, const float* __restrict__ pred,
    const float* __restrict__ inv, const float* __restrict__ signs,
    const int* __restrict__ heads, const int* __restrict__ tails,
    const uint16_t* __restrict__ W1T,   // [H=512][D=256] bf16
    const uint16_t* __restrict__ W2T,   // [D=256][H=512] bf16
    const float* __restrict__ b1, const float* __restrict__ b2,
    float* __restrict__ Out) {
  __shared__ __align__(16) uint16_t As[64 * 256];       // 32 KB, [kc=0..7][rr=0..63][32]
  __shared__ __align__(16) uint16_t Wb[2][SH * 256];    // 2x16 KB
  __shared__ __align__(16) uint16_t Hs[64 * HS_LD];     // 5 KB
  __shared__ __align__(16) float Cm[T_DIM][T_DIM];      // 1 KB combine matrix
  __shared__ int Lidx[T_DIM][2 * E_DIM];                // 4 KB: entry = (e<<1)|isInv
  __shared__ int Lcnt[T_DIM];
  __shared__ float sgnE[E_DIM];

  const int tid = threadIdx.x;
  const int b0 = blockIdx.x * 4;

  // ---- build combine matrix + per-t stream lists (round-8-verified scheme) ----
  Cm[tid >> 4][tid & 15] = ((tid >> 4) == (tid & 15)) ? EPS_F : 0.f;
  if (tid < T_DIM) Lcnt[tid] = 0;
  __syncthreads();
  if (tid < E_DIM) {
    const int e = tid;
    const int hh = heads[e] & (T_DIM - 1);
    const int tt = tails[e] & (T_DIM - 1);
    const float s = signs[e];
    sgnE[e] = s;
    atomicAdd(&Cm[tt][hh], s);                 // tail row gets s*term[head]
    int i = atomicAdd(&Lcnt[tt], 1);
    Lidx[tt][i] = e << 1;                      // pred stream
    atomicAdd(&Cm[hh][tt], s);                 // head row gets s*term[tail]
    i = atomicAdd(&Lcnt[hh], 1);
    Lidx[hh][i] = (e << 1) | 1;                // inv stream
  }
  __syncthreads();

  // ---- issue W1 slice 0 -> Wb[0] now (overlaps the agg phase; drained by barrier below)
#pragma unroll
  for (int p = 0; p < 4; ++p) {
    const int off = p * 2048 + tid * 8;          // == kc*1024 + hl*32 + c
    const int kc = off >> 10;
    const int hl = (off >> 5) & 31;
    const int c = off & 31;
    const uint16_t* g = W1T + (size_t)hl * D_DIM + kc * 32 + c;
    __builtin_amdgcn_global_load_lds((const GLOBAL_AS uint32_t*)g,
                                     (LDS_AS uint32_t*)(Wb[0] + off), 16, 0, 0);
  }

  // ---- agg phase: thread owns (bl = tid>>6, d0 = (tid&63)*4); term slices -> regs once
  const int bl = tid >> 6;
  const int d0 = (tid & 63) * 4;
  const size_t bb = (size_t)(b0 + bl) * D_DIM + d0;   // elem offset within one slice

  f32x4 tr[T_DIM];
#pragma unroll
  for (int s = 0; s < T_DIM; ++s)
    tr[s] = __builtin_nontemporal_load(reinterpret_cast<const f32x4*>(term + (size_t)s * BD_DIM + bb));

#pragma unroll 1
  for (int t = 0; t < T_DIM; ++t) {
    f32x4 cv[4];
#pragma unroll
    for (int q = 0; q < 4; ++q) cv[q] = *reinterpret_cast<const f32x4*>(&Cm[t][q * 4]);

    float acc[4] = {0.f, 0.f, 0.f, 0.f};
#pragma unroll
    for (int s = 0; s < T_DIM; ++s) {
      const float cs = cv[s >> 2][s & 3];
#pragma unroll
      for (int k = 0; k < 4; ++k) acc[k] += cs * tr[s][k];
    }

    const int n = Lcnt[t];
#pragma unroll 2
    for (int i = 0; i < n; ++i) {
      const int li = Lidx[t][i];
      const float* bp = ((li & 1) ? inv : pred) + (size_t)(li >> 1) * BD_DIM;
      const f32x4 p = __builtin_nontemporal_load(reinterpret_cast<const f32x4*>(bp + bb));
      const float sg = sgnE[li >> 1];
#pragma unroll
      for (int k = 0; k < 4; ++k) acc[k] += sg * p[k];
    }

    // write bf16x4 into As[kc][rr][c], rr = bl*16 + t (8-way write conflict, tiny volume)
    const int rr = bl * 16 + t;
    const int off = (d0 >> 5) * 2048 + rr * 32 + (d0 & 31);
    uint2 pk;
    pk.x = f2bf_rne(acc[0]) | (f2bf_rne(acc[1]) << 16);
    pk.y = f2bf_rne(acc[2]) | (f2bf_rne(acc[3]) << 16);
    *reinterpret_cast<uint2*>(As + off) = pk;
  }
  __syncthreads();   // As complete; W1 slice 0 resident

  // ---- MLP slice loop (round-7 verified structure, As already in LDS) ----
  const int w = tid >> 6;
  const int l = tid & 63;
  const int lane16 = l & 15;
  const int quad = l >> 4;
  const int wm  = (w & 1) * 32;
  const int wnA = ((w >> 1) & 1) * 16;
  const int wn2 = ((w >> 1) & 1) * 128;

  f32x4 oacc[2][8];
#pragma unroll
  for (int i = 0; i < 2; ++i)
#pragma unroll
    for (int j = 0; j < 8; ++j) oacc[i][j] = (f32x4){0.f, 0.f, 0.f, 0.f};

  for (int s = 0; s < NSLICE; ++s) {
    // phase A(s): issue W2 slice s -> Wb[1]; compute Hs = relu(As x W1_s + b1)
#pragma unroll
    for (int p = 0; p < 4; ++p) {
      const int off = p * 2048 + tid * 8;        // == d*32 + c
      const int d = off >> 5;
      const int c = off & 31;
      const uint16_t* g = W2T + (size_t)d * H_DIM + s * SH + c;
      __builtin_amdgcn_global_load_lds((const GLOBAL_AS uint32_t*)g,
                                       (LDS_AS uint32_t*)(Wb[1] + off), 16, 0, 0);
    }

    f32x4 hacc[2];
#pragma unroll
    for (int i = 0; i < 2; ++i) hacc[i] = (f32x4){0.f, 0.f, 0.f, 0.f};

#pragma unroll
    for (int kk = 0; kk < 8; ++kk) {
      short8 af[2], bfr;
      bfr = *reinterpret_cast<const short8*>(Wb[0] + kk * 1024 + (wnA + lane16) * 32 + quad * 8);
#pragma unroll
      for (int i = 0; i < 2; ++i)
        af[i] = *reinterpret_cast<const short8*>(As + kk * 2048 + (wm + i * 16 + lane16) * 32 + quad * 8);
#pragma unroll
      for (int i = 0; i < 2; ++i)
        hacc[i] = __builtin_amdgcn_mfma_f32_16x16x32_bf16(af[i], bfr, hacc[i], 0, 0, 0);
    }

    {
      const int hloc = wnA + lane16;
      const float bv = b1[s * SH + hloc];
#pragma unroll
      for (int i = 0; i < 2; ++i) {
#pragma unroll
        for (int r = 0; r < 4; ++r) {
          const int row = wm + i * 16 + quad * 4 + r;
          const float x = fmaxf(hacc[i][r] + bv, 0.f);
          Hs[row * HS_LD + hloc] = (uint16_t)f2bf_rne(x);
        }
      }
    }
    __syncthreads();   // Hs visible; W2 slice s resident; Wb[0] free

    // phase B(s): issue W1 slice s+1 -> Wb[0]; oacc += Hs x W2_s
    if (s < NSLICE - 1) {
#pragma unroll
      for (int p = 0; p < 4; ++p) {
        const int off = p * 2048 + tid * 8;
        const int kc = off >> 10;
        const int hl = (off >> 5) & 31;
        const int c = off & 31;
        const uint16_t* g = W1T + (size_t)((s + 1) * SH + hl) * D_DIM + kc * 32 + c;
        __builtin_amdgcn_global_load_lds((const GLOBAL_AS uint32_t*)g,
                                         (LDS_AS uint32_t*)(Wb[0] + off), 16, 0, 0);
      }
    }

    {
      short8 af2[2], bf2[8];
#pragma unroll
      for (int i = 0; i < 2; ++i)
        af2[i] = *reinterpret_cast<const short8*>(Hs + (wm + i * 16 + lane16) * HS_LD + quad * 8);
#pragma unroll
      for (int j = 0; j < 8; ++j)
        bf2[j] = *reinterpret_cast<const short8*>(Wb[1] + (wn2 + j * 16 + lane16) * 32 + quad * 8);
#pragma unroll
      for (int i = 0; i < 2; ++i)
#pragma unroll
        for (int j = 0; j < 8; ++j)
          oacc[i][j] = __builtin_amdgcn_mfma_f32_16x16x32_bf16(af2[i], bf2[j], oacc[i][j], 0, 0, 0);
    }
    __syncthreads();   // Hs/Wb[1] free; W1 slice s+1 resident
  }

  // ---- epilogue: Out[t*B + b0 + bl][col], tile row rr = bl*16 + t ----
#pragma unroll
  for (int j = 0; j < 8; ++j) {
    const int col = wn2 + j * 16 + lane16;
    const float bv = b2[col];
#pragma unroll
    for (int i = 0; i < 2; ++i) {
#pragma unroll
      for (int r = 0; r < 4; ++r) {
        const int rr = wm + i * 16 + quad * 4 + r;          // 0..63
        const size_t grow = (size_t)(rr & 15) * B_DIM + b0 + (rr >> 4);
        __builtin_nontemporal_store(oacc[i][j][r] + bv, Out + grow * D_DIM + col);
      }
    }
  }
}

extern "C" void kernel_launch(void* const* d_in, const int* in_sizes, int n_in,
                              void* d_out, int out_size, void* d_ws, size_t ws_size,
                              hipStream_t stream) {
  const float* term  = (const float*)d_in[0];
  const float* pred  = (const float*)d_in[1];
  const float* inv   = (const float*)d_in[2];
  const float* signs = (const float*)d_in[3];
  const float* W1    = (const float*)d_in[4];
  const float* b1    = (const float*)d_in[5];
  const float* W2    = (const float*)d_in[6];
  const float* b2    = (const float*)d_in[7];
  const int* heads   = (const int*)d_in[8];
  const int* tails   = (const int*)d_in[9];

  char* ws = (char*)d_ws;
  uint16_t* W1T = (uint16_t*)(ws);              // 512*256*2 = 256 KB
  uint16_t* W2T = (uint16_t*)(ws + 262144);     // 256*512*2 = 256 KB

  prep_kernel<<<dim3(512), dim3(256), 0, stream>>>(W1, W2, W1T, W2T);
  fused_all<<<dim3(B_DIM / 4), dim3(256), 0, stream>>>(
      term, pred, inv, signs, heads, tails, W1T, W2T, b1, b2, (float*)d_out);
}

// Round 10
// 392.373 us; speedup vs baseline: 1.0972x; 1.0006x over previous
//
#include <hip/hip_runtime.h>
#include <hip/hip_bf16.h>
#include <stdint.h>

#define T_DIM 16
#define B_DIM 4096
#define D_DIM 256
#define H_DIM 512
#define E_DIM 32
#define M_DIM (T_DIM * B_DIM)
#define BD_DIM (B_DIM * D_DIM)     // elems per term/pred slice
#define EPS_F 0.1f

#define NSLICE 16                  // H / SH
#define SH 32                      // h-columns per slice
#define HS_LD 40                   // Hs leading dim (pad 32->40: 16B-aligned b128, bank-spread)
#define MAXS 64

typedef __attribute__((ext_vector_type(8))) short short8;   // 8 bf16 (MFMA A/B frag)
typedef __attribute__((ext_vector_type(4))) float f32x4;    // MFMA C/D frag; clang vec (nontemporal ok)

#define GLOBAL_AS __attribute__((address_space(1)))
#define LDS_AS __attribute__((address_space(3)))

__device__ __forceinline__ uint32_t f2bf_rne(float x) {
  uint32_t u = __float_as_uint(x);
  return (u + 0x7fffu + ((u >> 16) & 1u)) >> 16;
}

// ---- agg v5 (reg-resident term, 4-elem chunks for 2x grid) + prep rider ----
// Lesson from rounds 8/9: the reg-resident agg (352 MB total traffic, proven correct)
// was GRID-starved at 512 blocks (8 waves/CU). 4-elem chunks -> 1024 blocks ->
// 16 waves/CU; t-loop unroll 2 pipelines the stream loads across t-iterations.
// blockIdx.x >= 1024 -> weight-prep path (free rider).
__global__ __launch_bounds__(256) void agg_prep_kernel(
    const float* __restrict__ term, const float* __restrict__ pred,
    const float* __restrict__ inv, const float* __restrict__ signs,
    const int* __restrict__ heads, const int* __restrict__ tails,
    const float* __restrict__ W1, const float* __restrict__ W2,
    uint16_t* __restrict__ agg, uint16_t* __restrict__ W1T, uint16_t* __restrict__ W2T) {
  const int tid = threadIdx.x;
  if (blockIdx.x >= 1024) {  // ---- prep path ----
    const int idx = (blockIdx.x - 1024) * 256 + tid;    // 0 .. 131071 == D*H
    const int d = idx >> 9, h = idx & (H_DIM - 1);
    W1T[h * D_DIM + d] = (uint16_t)f2bf_rne(W1[idx]);
    const int h2 = idx >> 8, d2 = idx & (D_DIM - 1);
    W2T[d2 * H_DIM + h2] = (uint16_t)f2bf_rne(W2[idx]);
    return;
  }

  __shared__ float Cm[T_DIM][T_DIM];      // combine matrix: agg[t] = sum_s Cm[t][s]*term[s] + streams
  __shared__ float Lsgn[T_DIM][MAXS];
  __shared__ uint64_t Lptr[T_DIM][MAXS];
  __shared__ int Lcnt[T_DIM];

  Cm[tid >> 4][tid & 15] = ((tid >> 4) == (tid & 15)) ? EPS_F : 0.f;
  if (tid < T_DIM) Lcnt[tid] = 0;
  __syncthreads();
  if (tid < E_DIM) {   // parallel build (round-8 verified)
    const int e = tid;
    const int hh = heads[e] & (T_DIM - 1);
    const int tt = tails[e] & (T_DIM - 1);
    const float s = signs[e];
    atomicAdd(&Cm[tt][hh], s);
    int i = atomicAdd(&Lcnt[tt], 1);
    Lsgn[tt][i] = s; Lptr[tt][i] = (uint64_t)(pred + (size_t)e * BD_DIM);
    atomicAdd(&Cm[hh][tt], s);
    i = atomicAdd(&Lcnt[hh], 1);
    Lsgn[hh][i] = s; Lptr[hh][i] = (uint64_t)(inv + (size_t)e * BD_DIM);
  }
  __syncthreads();

  const int j = (blockIdx.x * 256 + tid) * 4;   // 4-elem chunk in [0, B*D)

  // all 16 term slices for this chunk -> registers, read once (nt)
  f32x4 tr[T_DIM];
#pragma unroll
  for (int s = 0; s < T_DIM; ++s)
    tr[s] = __builtin_nontemporal_load(reinterpret_cast<const f32x4*>(term + (size_t)s * BD_DIM + j));

#pragma unroll 2
  for (int t = 0; t < T_DIM; ++t) {
    f32x4 cv[4];
#pragma unroll
    for (int q = 0; q < 4; ++q) cv[q] = *reinterpret_cast<const f32x4*>(&Cm[t][q * 4]);

    float acc[4] = {0.f, 0.f, 0.f, 0.f};
#pragma unroll
    for (int s = 0; s < T_DIM; ++s) {
      const float cs = cv[s >> 2][s & 3];
#pragma unroll
      for (int k = 0; k < 4; ++k) acc[k] += cs * tr[s][k];
    }

    const int n = Lcnt[t];
#pragma unroll 2
    for (int i = 0; i < n; ++i) {
      const float sg = Lsgn[t][i];
      const float* bp = (const float*)Lptr[t][i];
      const f32x4 p = __builtin_nontemporal_load(reinterpret_cast<const f32x4*>(bp + j));
#pragma unroll
      for (int k = 0; k < 4; ++k) acc[k] += sg * p[k];
    }

    uint2 pk;
    pk.x = f2bf_rne(acc[0]) | (f2bf_rne(acc[1]) << 16);
    pk.y = f2bf_rne(acc[2]) | (f2bf_rne(acc[3]) << 16);
    *reinterpret_cast<uint2*>(agg + (size_t)t * BD_DIM + j) = pk;
  }
}

// ---- fused MLP (round-7 verified, byte-identical) ----
// out[M,256] = relu(agg[M,256] x W1T^T + b1) x W2T^T + b2; 64-row tiles, 2 blocks/CU.
__global__ __launch_bounds__(256, 2) void mlp_fused(
    const uint16_t* __restrict__ A,     // agg, [M][256] bf16
    const uint16_t* __restrict__ W1T,   // [H=512][D=256] bf16
    const uint16_t* __restrict__ W2T,   // [D=256][H=512] bf16
    const float* __restrict__ b1, const float* __restrict__ b2,
    float* __restrict__ Out) {
  __shared__ __align__(16) uint16_t As[64 * 256];       // 32 KB, [kc=0..7][row=0..63][32]
  __shared__ __align__(16) uint16_t Wb[2][SH * 256];    // 2x16 KB
  __shared__ __align__(16) uint16_t Hs[64 * HS_LD];     // 5 KB

  const int tid = threadIdx.x;
  const int w = tid >> 6;
  const int l = tid & 63;
  const int lane16 = l & 15;
  const int quad = l >> 4;
  const int m0 = blockIdx.x * 64;

  const int wm  = (w & 1) * 32;
  const int wnA = ((w >> 1) & 1) * 16;
  const int wn2 = ((w >> 1) & 1) * 128;

  // ---- stage A-chunk; LDS dest == linear byte off (gload_lds contract) ----
#pragma unroll
  for (int p = 0; p < 8; ++p) {
    const int off = p * 2048 + tid * 8;          // == kc*2048 + row*32 + c
    const int kc = off >> 11;
    const int row = (off >> 5) & 63;
    const int c = off & 31;
    const uint16_t* g = A + (size_t)(m0 + row) * D_DIM + kc * 32 + c;
    __builtin_amdgcn_global_load_lds((const GLOBAL_AS uint32_t*)g,
                                     (LDS_AS uint32_t*)(As + off), 16, 0, 0);
  }
  // ---- stage W1 slice 0 into Wb[0] ----
#pragma unroll
  for (int p = 0; p < 4; ++p) {
    const int off = p * 2048 + tid * 8;          // == kc*1024 + hl*32 + c
    const int kc = off >> 10;
    const int hl = (off >> 5) & 31;
    const int c = off & 31;
    const uint16_t* g = W1T + (size_t)hl * D_DIM + kc * 32 + c;
    __builtin_amdgcn_global_load_lds((const GLOBAL_AS uint32_t*)g,
                                     (LDS_AS uint32_t*)(Wb[0] + off), 16, 0, 0);
  }
  __syncthreads();

  f32x4 oacc[2][8];
#pragma unroll
  for (int i = 0; i < 2; ++i)
#pragma unroll
    for (int j = 0; j < 8; ++j) oacc[i][j] = (f32x4){0.f, 0.f, 0.f, 0.f};

  for (int s = 0; s < NSLICE; ++s) {
    // phase A(s): issue W2 slice s -> Wb[1]; compute Hs = relu(As x W1_s + b1)
#pragma unroll
    for (int p = 0; p < 4; ++p) {
      const int off = p * 2048 + tid * 8;        // == d*32 + c
      const int d = off >> 5;
      const int c = off & 31;
      const uint16_t* g = W2T + (size_t)d * H_DIM + s * SH + c;
      __builtin_amdgcn_global_load_lds((const GLOBAL_AS uint32_t*)g,
                                       (LDS_AS uint32_t*)(Wb[1] + off), 16, 0, 0);
    }

    f32x4 hacc[2];
#pragma unroll
    for (int i = 0; i < 2; ++i) hacc[i] = (f32x4){0.f, 0.f, 0.f, 0.f};

#pragma unroll
    for (int kk = 0; kk < 8; ++kk) {
      short8 af[2], bfr;
      bfr = *reinterpret_cast<const short8*>(Wb[0] + kk * 1024 + (wnA + lane16) * 32 + quad * 8);
#pragma unroll
      for (int i = 0; i < 2; ++i)
        af[i] = *reinterpret_cast<const short8*>(As + kk * 2048 + (wm + i * 16 + lane16) * 32 + quad * 8);
#pragma unroll
      for (int i = 0; i < 2; ++i)
        hacc[i] = __builtin_amdgcn_mfma_f32_16x16x32_bf16(af[i], bfr, hacc[i], 0, 0, 0);
    }

    {
      const int hloc = wnA + lane16;
      const float bv = b1[s * SH + hloc];
#pragma unroll
      for (int i = 0; i < 2; ++i) {
#pragma unroll
        for (int r = 0; r < 4; ++r) {
          const int row = wm + i * 16 + quad * 4 + r;
          const float x = fmaxf(hacc[i][r] + bv, 0.f);
          Hs[row * HS_LD + hloc] = (uint16_t)f2bf_rne(x);
        }
      }
    }
    __syncthreads();   // Hs visible; W2 slice s resident; Wb[0] free

    // phase B(s): issue W1 slice s+1 -> Wb[0]; oacc += Hs x W2_s
    if (s < NSLICE - 1) {
#pragma unroll
      for (int p = 0; p < 4; ++p) {
        const int off = p * 2048 + tid * 8;
        const int kc = off >> 10;
        const int hl = (off >> 5) & 31;
        const int c = off & 31;
        const uint16_t* g = W1T + (size_t)((s + 1) * SH + hl) * D_DIM + kc * 32 + c;
        __builtin_amdgcn_global_load_lds((const GLOBAL_AS uint32_t*)g,
                                         (LDS_AS uint32_t*)(Wb[0] + off), 16, 0, 0);
      }
    }

    {
      short8 af2[2], bf2[8];
#pragma unroll
      for (int i = 0; i < 2; ++i)
        af2[i] = *reinterpret_cast<const short8*>(Hs + (wm + i * 16 + lane16) * HS_LD + quad * 8);
#pragma unroll
      for (int j = 0; j < 8; ++j)
        bf2[j] = *reinterpret_cast<const short8*>(Wb[1] + (wn2 + j * 16 + lane16) * 32 + quad * 8);
#pragma unroll
      for (int i = 0; i < 2; ++i)
#pragma unroll
        for (int j = 0; j < 8; ++j)
          oacc[i][j] = __builtin_amdgcn_mfma_f32_16x16x32_bf16(af2[i], bf2[j], oacc[i][j], 0, 0, 0);
    }
    __syncthreads();   // Hs/Wb[1] free; W1 slice s+1 resident
  }

  // ---- final epilogue ----
#pragma unroll
  for (int j = 0; j < 8; ++j) {
    const int col = wn2 + j * 16 + lane16;
    const float bv = b2[col];
#pragma unroll
    for (int i = 0; i < 2; ++i) {
#pragma unroll
      for (int r = 0; r < 4; ++r) {
        const int row = m0 + wm + i * 16 + quad * 4 + r;
        Out[(size_t)row * D_DIM + col] = oacc[i][j][r] + bv;
      }
    }
  }
}

extern "C" void kernel_launch(void* const* d_in, const int* in_sizes, int n_in,
                              void* d_out, int out_size, void* d_ws, size_t ws_size,
                              hipStream_t stream) {
  const float* term  = (const float*)d_in[0];
  const float* pred  = (const float*)d_in[1];
  const float* inv   = (const float*)d_in[2];
  const float* signs = (const float*)d_in[3];
  const float* W1    = (const float*)d_in[4];
  const float* b1    = (const float*)d_in[5];
  const float* W2    = (const float*)d_in[6];
  const float* b2    = (const float*)d_in[7];
  const int* heads   = (const int*)d_in[8];
  const int* tails   = (const int*)d_in[9];

  char* ws = (char*)d_ws;
  uint16_t* W1T = (uint16_t*)(ws);              // 256 KB
  uint16_t* W2T = (uint16_t*)(ws + 262144);     // 256 KB
  uint16_t* agg = (uint16_t*)(ws + 524288);     // 32 MB

  // dispatch 1: agg v5 (blocks 0..1023, 4-elem chunks) + prep (blocks 1024..1535)
  agg_prep_kernel<<<dim3(1536), dim3(256), 0, stream>>>(
      term, pred, inv, signs, heads, tails, W1, W2, agg, W1T, W2T);
  // dispatch 2: fused MLP (64-row tiles, 2 blocks/CU)
  mlp_fused<<<dim3(M_DIM / 64), dim3(256), 0, stream>>>(
      agg, W1T, W2T, b1, b2, (float*)d_out);
}